// Round 5
// baseline (282.146 us; speedup 1.0000x reference)
//
#include <hip/hip_runtime.h>

typedef unsigned short u16;
typedef short bf16x8 __attribute__((ext_vector_type(8)));
typedef float f32x4 __attribute__((ext_vector_type(4)));

typedef __attribute__((address_space(3))) unsigned int lds_uint;
typedef __attribute__((address_space(1))) const unsigned int glob_uint;

__device__ __forceinline__ void gll16(const void* g, void* l) {
    __builtin_amdgcn_global_load_lds((glob_uint*)g, (lds_uint*)l, 16, 0, 0);
}

__device__ __forceinline__ u16 f2b(float f) {
    union { float f; unsigned int u; } cv; cv.f = f;
    unsigned int u = cv.u;
    u += 0x7fffu + ((u >> 16) & 1u);
    return (u16)(u >> 16);
}

__device__ __forceinline__ uint2 pack4(float a, float b, float c, float d) {
    uint2 r;
    r.x = (unsigned int)f2b(a) | ((unsigned int)f2b(b) << 16);
    r.y = (unsigned int)f2b(c) | ((unsigned int)f2b(d) << 16);
    return r;
}

// ---------------- prep: weight transpose + bf16 convert ----------------
// wqkvT[n][k], n: [0,512)=Q [512,1024)=K [1024,1536)=V; woT[n][k]=wo[k][n]
__global__ void prep_kernel(const float* __restrict__ wq, const float* __restrict__ wk,
                            const float* __restrict__ wv, const float* __restrict__ wo,
                            const float* __restrict__ bq, const float* __restrict__ bk,
                            const float* __restrict__ bv,
                            u16* __restrict__ wqkvT, u16* __restrict__ woT,
                            float* __restrict__ biasq) {
    int idx = blockIdx.x * 256 + threadIdx.x;
    const int N1 = 512 * 1536;
    const int N2 = 512 * 512;
    if (idx < N1) {
        int k = idx / 1536, n = idx % 1536;
        int which = n >> 9, nn = n & 511;
        const float* w = (which == 0) ? wq : (which == 1) ? wk : wv;
        wqkvT[n * 512 + k] = f2b(w[k * 512 + nn]);
    } else if (idx < N1 + N2) {
        int j = idx - N1;
        int k = j / 512, n = j % 512;
        woT[n * 512 + k] = f2b(wo[k * 512 + n]);
    } else if (idx < N1 + N2 + 1536) {
        int n = idx - N1 - N2;
        biasq[n] = (n < 512) ? bq[n] : (n < 1024) ? bk[n - 512] : bv[n - 1024];
    }
}

// ---------------- pre: x fp32 -> bf16, window-shift permuted ----------------
__global__ __launch_bounds__(256) void pre_kernel(const float* __restrict__ x,
                                                  u16* __restrict__ xw) {
    int idx = blockIdx.x * 256 + threadIdx.x;      // 8 elems per thread
    int row = idx >> 6;
    int c = (idx & 63) * 8;
    int b_ = row >> 12, win = (row >> 6) & 63, t = row & 63;
    int wi = win >> 3, wj = win & 7, ti = t >> 3, tj = t & 7;
    int hh = (wi * 8 + ti + 4) & 63, ww = (wj * 8 + tj + 4) & 63;
    const float* src = x + ((size_t)b_ * 4096 + hh * 64 + ww) * 512 + c;
    float4 v0 = *(const float4*)src;
    float4 v1 = *(const float4*)(src + 4);
    ushort4 p0, p1;
    p0.x = f2b(v0.x); p0.y = f2b(v0.y); p0.z = f2b(v0.z); p0.w = f2b(v0.w);
    p1.x = f2b(v1.x); p1.y = f2b(v1.y); p1.z = f2b(v1.z); p1.w = f2b(v1.w);
    u16* dst = xw + (size_t)row * 512 + c;
    *(ushort4*)dst = p0;
    *(ushort4*)(dst + 4) = p1;
}

// ---------------- QKV GEMM: M=32768 N=1536 K=512, BK=64 ----------------
// Swapped MFMA; epilogue staged through LDS for full-line coalesced stores.
__global__ __launch_bounds__(256) void qkv_gemm(const u16* __restrict__ xw,
        const u16* __restrict__ wqkvT, const float* __restrict__ biasq,
        u16* __restrict__ qkvb) {
    __shared__ u16 S[16384];           // As | Bs in K-loop; 128x128 tile in epilogue
    u16* As = S;
    u16* Bs = S + 8192;
    const int tid = threadIdx.x;
    const int lane = tid & 63, wid = tid >> 6;
    const int wr = wid >> 1, wc = wid & 1;
    const int m = lane & 15, qd = lane >> 4;
    // XCD-aware swizzle: each XCD (bid&7) owns a contiguous band of 32 row-blocks
    const int g = blockIdx.x >> 3, x8 = blockIdx.x & 7;
    const int bx = g % 12, by = g / 12 + x8 * 32;
    const int rowBase = by * 128;
    const int colBase = bx * 128;
    const int c8 = (lane & 7) ^ (lane >> 3);

    f32x4 acc[4][4];
#pragma unroll
    for (int i = 0; i < 4; ++i)
#pragma unroll
        for (int j = 0; j < 4; ++j) acc[i][j] = (f32x4){0.f, 0.f, 0.f, 0.f};

    for (int kt = 0; kt < 8; ++kt) {
        const int k0 = kt * 64;
        __syncthreads();
#pragma unroll
        for (int j = 0; j < 4; ++j) {
            int q = (j * 4 + wid) * 64 + lane;
            int r = (j * 4 + wid) * 8 + (lane >> 3);
            gll16(xw + (size_t)(rowBase + r) * 512 + k0 + c8 * 8, &As[q * 8]);
            gll16(wqkvT + (size_t)(colBase + r) * 512 + k0 + c8 * 8, &Bs[q * 8]);
        }
        __syncthreads();
#pragma unroll
        for (int s = 0; s < 2; ++s) {
            bf16x8 a[4], b[4];
#pragma unroll
            for (int ni = 0; ni < 4; ++ni) {
                int R = wc * 64 + ni * 16 + m;
                b[ni] = *(const bf16x8*)&Bs[R * 64 + (((s * 4 + qd) ^ (R & 7)) * 8)];
            }
#pragma unroll
            for (int mi = 0; mi < 4; ++mi) {
                int R = wr * 64 + mi * 16 + m;
                a[mi] = *(const bf16x8*)&As[R * 64 + (((s * 4 + qd) ^ (R & 7)) * 8)];
            }
            // swapped: D[row = col-dim local qd*4+rr][col = token local m]
#pragma unroll
            for (int mi = 0; mi < 4; ++mi)
#pragma unroll
                for (int ni = 0; ni < 4; ++ni)
                    acc[mi][ni] = __builtin_amdgcn_mfma_f32_16x16x32_bf16(b[ni], a[mi], acc[mi][ni], 0, 0, 0);
        }
    }

    // ---- epilogue: bias add, pack bf16, stage tile in LDS (XOR-swizzled) ----
    __syncthreads();
#pragma unroll
    for (int mi = 0; mi < 4; ++mi) {
        int r = wr * 64 + mi * 16 + m;     // token local
#pragma unroll
        for (int ni = 0; ni < 4; ++ni) {
            int ch = wc * 8 + ni * 2 + (qd >> 1);       // logical 8-u16 chunk
            float4 bb = *(const float4*)&biasq[colBase + wc * 64 + ni * 16 + qd * 4];
            uint2 pk = pack4(acc[mi][ni][0] + bb.x, acc[mi][ni][1] + bb.y,
                             acc[mi][ni][2] + bb.z, acc[mi][ni][3] + bb.w);
            *(uint2*)&S[r * 128 + ((ch ^ (r & 15)) * 8) + (qd & 1) * 4] = pk;
        }
    }
    __syncthreads();
    // ---- coalesced store: 8 rows x 128 B full lines per instruction ----
#pragma unroll
    for (int it = 0; it < 4; ++it) {
        int r = it * 32 + (tid >> 3);
        int cb = (tid & 7) * 2;
#pragma unroll
        for (int cc = 0; cc < 2; ++cc) {
            int pc = (cb + cc) ^ (r & 15);
            uint4 v = *(const uint4*)&S[r * 128 + pc * 8];
            *(uint4*)&qkvb[(size_t)(rowBase + r) * 1536 + colBase + (cb + cc) * 8] = v;
        }
    }
}

// ---------------- attention: one wave per (window, head) ----------------
__global__ __launch_bounds__(256) void attn_kernel(const u16* __restrict__ qkvb,
                                                   u16* __restrict__ ows) {
    __shared__ u16 Sb[4 * 64 * 72];   // per-wave scratch: P, then V^T
    const int tid = threadIdx.x, lane = tid & 63, wid = tid >> 6;
    const int task = blockIdx.x * 4 + wid;
    const int win = task >> 3, h = task & 7;
    const int m = lane & 15, qd = lane >> 4;
    const u16* base = qkvb + (size_t)win * 64 * 1536;
    u16* Sl = Sb + wid * 64 * 72;

    // Q, K fragments (16B loads)
    bf16x8 qa[4][2], ka[4][2];
#pragma unroll
    for (int mi = 0; mi < 4; ++mi)
#pragma unroll
        for (int s = 0; s < 2; ++s) {
            const u16* p = base + (size_t)(mi * 16 + m) * 1536 + h * 64 + s * 32 + qd * 8;
            qa[mi][s] = *(const bf16x8*)p;
            ka[mi][s] = *(const bf16x8*)(p + 512);
        }

    f32x4 sa[4][4];
#pragma unroll
    for (int i = 0; i < 4; ++i)
#pragma unroll
        for (int j = 0; j < 4; ++j) sa[i][j] = (f32x4){0.f, 0.f, 0.f, 0.f};
#pragma unroll
    for (int mi = 0; mi < 4; ++mi)
#pragma unroll
        for (int ni = 0; ni < 4; ++ni)
#pragma unroll
            for (int s = 0; s < 2; ++s)
                sa[mi][ni] = __builtin_amdgcn_mfma_f32_16x16x32_bf16(qa[mi][s], ka[ni][s], sa[mi][ni], 0, 0, 0);

    // softmax; write P into Sl (row stride 72)
    const float c1 = 0.125f * 1.4426950408889634f;
#pragma unroll
    for (int mi = 0; mi < 4; ++mi) {
#pragma unroll
        for (int rr = 0; rr < 4; ++rr) {
            float mx = -3.4e38f;
#pragma unroll
            for (int ni = 0; ni < 4; ++ni) mx = fmaxf(mx, sa[mi][ni][rr]);
            mx = fmaxf(mx, __shfl_xor(mx, 1, 64));
            mx = fmaxf(mx, __shfl_xor(mx, 2, 64));
            mx = fmaxf(mx, __shfl_xor(mx, 4, 64));
            mx = fmaxf(mx, __shfl_xor(mx, 8, 64));
            float sum = 0.f;
#pragma unroll
            for (int ni = 0; ni < 4; ++ni) {
                float p = exp2f((sa[mi][ni][rr] - mx) * c1);
                sa[mi][ni][rr] = p;
                sum += p;
            }
            sum += __shfl_xor(sum, 1, 64);
            sum += __shfl_xor(sum, 2, 64);
            sum += __shfl_xor(sum, 4, 64);
            sum += __shfl_xor(sum, 8, 64);
            float inv = 1.f / sum;
            int row = mi * 16 + qd * 4 + rr;
#pragma unroll
            for (int ni = 0; ni < 4; ++ni)
                Sl[row * 72 + ni * 16 + m] = f2b(sa[mi][ni][rr] * inv);
        }
    }

    // P A-fragments
    bf16x8 pa[4][2];
#pragma unroll
    for (int mi = 0; mi < 4; ++mi)
#pragma unroll
        for (int s = 0; s < 2; ++s)
            pa[mi][s] = *(const bf16x8*)&Sl[(mi * 16 + m) * 72 + s * 32 + qd * 8];

    // build V^T in Sl: lane loads (t = it*16+m, d = qd*16..+16), scatters 2B
#pragma unroll
    for (int it = 0; it < 4; ++it) {
        int t = it * 16 + m;
        const u16* vp = base + (size_t)t * 1536 + 1024 + h * 64 + qd * 16;
        bf16x8 v0 = *(const bf16x8*)vp;
        bf16x8 v1 = *(const bf16x8*)(vp + 8);
#pragma unroll
        for (int k = 0; k < 8; ++k) {
            Sl[(qd * 16 + k) * 72 + t] = ((const u16*)&v0)[k];
            Sl[(qd * 16 + 8 + k) * 72 + t] = ((const u16*)&v1)[k];
        }
    }

    f32x4 oa[4][4];
#pragma unroll
    for (int i = 0; i < 4; ++i)
#pragma unroll
        for (int j = 0; j < 4; ++j) oa[i][j] = (f32x4){0.f, 0.f, 0.f, 0.f};
#pragma unroll
    for (int ni = 0; ni < 4; ++ni)
#pragma unroll
        for (int s = 0; s < 2; ++s) {
            bf16x8 vf = *(const bf16x8*)&Sl[(ni * 16 + m) * 72 + s * 32 + qd * 8];
#pragma unroll
            for (int mi = 0; mi < 4; ++mi)
                oa[mi][ni] = __builtin_amdgcn_mfma_f32_16x16x32_bf16(vf, pa[mi][s], oa[mi][ni], 0, 0, 0);
        }

    // O store: D[d][q] -> packed uint2 (4 consecutive d per lane)
#pragma unroll
    for (int mi = 0; mi < 4; ++mi) {
        u16* dst = ows + (size_t)(win * 64 + mi * 16 + m) * 512 + h * 64;
#pragma unroll
        for (int ni = 0; ni < 4; ++ni)
            *(uint2*)&dst[ni * 16 + qd * 4] =
                pack4(oa[mi][ni][0], oa[mi][ni][1], oa[mi][ni][2], oa[mi][ni][3]);
    }
}

// ---------------- proj GEMM: M=32768 N=512 K=512, BK=64 ----------------
// Swapped MFMA; LDS-staged fp32 epilogue with full-line stores + bias + residual.
__global__ __launch_bounds__(256) void proj_gemm(const u16* __restrict__ ows,
        const u16* __restrict__ woT, const float* __restrict__ bo,
        const float* __restrict__ x, float* __restrict__ out) {
    __shared__ float Sf[8192];         // 32 KB: As|Bs in K-loop, 64x128 f32 epilogue
    u16* As = (u16*)Sf;
    u16* Bs = (u16*)Sf + 8192;
    const int tid = threadIdx.x;
    const int lane = tid & 63, wid = tid >> 6;
    const int wr = wid >> 1, wc = wid & 1;
    const int m = lane & 15, qd = lane >> 4;
    const int g = blockIdx.x >> 3, x8 = blockIdx.x & 7;
    const int bx = g & 3, by = (g >> 2) + x8 * 32;
    const int rowBase = by * 128;
    const int colBase = bx * 128;
    const int c8 = (lane & 7) ^ (lane >> 3);

    f32x4 acc[4][4];
#pragma unroll
    for (int i = 0; i < 4; ++i)
#pragma unroll
        for (int j = 0; j < 4; ++j) acc[i][j] = (f32x4){0.f, 0.f, 0.f, 0.f};

    for (int kt = 0; kt < 8; ++kt) {
        const int k0 = kt * 64;
        __syncthreads();
#pragma unroll
        for (int j = 0; j < 4; ++j) {
            int q = (j * 4 + wid) * 64 + lane;
            int r = (j * 4 + wid) * 8 + (lane >> 3);
            gll16(ows + (size_t)(rowBase + r) * 512 + k0 + c8 * 8, &As[q * 8]);
            gll16(woT + (size_t)(colBase + r) * 512 + k0 + c8 * 8, &Bs[q * 8]);
        }
        __syncthreads();
#pragma unroll
        for (int s = 0; s < 2; ++s) {
            bf16x8 a[4], b[4];
#pragma unroll
            for (int ni = 0; ni < 4; ++ni) {
                int R = wc * 64 + ni * 16 + m;
                b[ni] = *(const bf16x8*)&Bs[R * 64 + (((s * 4 + qd) ^ (R & 7)) * 8)];
            }
#pragma unroll
            for (int mi = 0; mi < 4; ++mi) {
                int R = wr * 64 + mi * 16 + m;
                a[mi] = *(const bf16x8*)&As[R * 64 + (((s * 4 + qd) ^ (R & 7)) * 8)];
            }
#pragma unroll
            for (int mi = 0; mi < 4; ++mi)
#pragma unroll
                for (int ni = 0; ni < 4; ++ni)
                    acc[mi][ni] = __builtin_amdgcn_mfma_f32_16x16x32_bf16(b[ni], a[mi], acc[mi][ni], 0, 0, 0);
        }
    }

    // ---- epilogue: two passes of 64 token-rows through LDS ----
#pragma unroll
    for (int p = 0; p < 2; ++p) {
        __syncthreads();
        if (wr == p) {
#pragma unroll
            for (int mi = 0; mi < 4; ++mi) {
                int row = mi * 16 + m;                    // token within pass
#pragma unroll
                for (int ni = 0; ni < 4; ++ni) {
                    int c = wc * 16 + ni * 4 + qd;        // 16B f32 chunk 0..31
                    *(f32x4*)&Sf[row * 128 + ((c ^ (row & 7)) * 4)] = acc[mi][ni];
                }
            }
        }
        __syncthreads();
#pragma unroll
        for (int sub = 0; sub < 2; ++sub) {
            int row = sub * 32 + (tid >> 3);
            int rowg = rowBase + p * 64 + row;            // win*64 + t
            int win = rowg >> 6, t = rowg & 63;
            int b_ = win >> 6, wh = (win >> 3) & 7, ww_ = win & 7;
            int ti = t >> 3, tj = t & 7;
            int hh = (wh * 8 + ti + 4) & 63;
            int www = (ww_ * 8 + tj + 4) & 63;
            size_t tok = (size_t)b_ * 4096 + hh * 64 + www;
#pragma unroll
            for (int j = 0; j < 4; ++j) {
                int c = (tid & 7) * 4 + j;
                f32x4 v = *(const f32x4*)&Sf[row * 128 + ((c ^ (row & 7)) * 4)];
                int col0 = colBase + c * 4;
                float4 bv = *(const float4*)&bo[col0];
                float4 xv = *(const float4*)&x[tok * 512 + col0];
                float4 o;
                o.x = v[0] + bv.x + xv.x;
                o.y = v[1] + bv.y + xv.y;
                o.z = v[2] + bv.z + xv.z;
                o.w = v[3] + bv.w + xv.w;
                *(float4*)&out[tok * 512 + col0] = o;
            }
        }
    }
}

extern "C" void kernel_launch(void* const* d_in, const int* in_sizes, int n_in,
                              void* d_out, int out_size, void* d_ws, size_t ws_size,
                              hipStream_t stream) {
    const float* x  = (const float*)d_in[0];
    const float* wq = (const float*)d_in[1];
    const float* bq = (const float*)d_in[2];
    const float* wk = (const float*)d_in[3];
    const float* bk = (const float*)d_in[4];
    const float* wv = (const float*)d_in[5];
    const float* bv = (const float*)d_in[6];
    const float* wo = (const float*)d_in[7];
    const float* bo = (const float*)d_in[8];
    float* out = (float*)d_out;
    char* ws = (char*)d_ws;

    u16*   wqkvT = (u16*)ws;                               // 1536*512*2
    u16*   woT   = (u16*)(ws + 1572864);                   // 512*512*2
    float* biasq = (float*)(ws + 1572864 + 524288);        // 1536*4
    size_t off = 2103296;
    u16* xw   = (u16*)(ws + off);                          // 32768*512  u16 = 32 MiB
    u16* qkvb = xw + (size_t)16777216;                     // 32768*1536 u16 = 96 MiB
    u16* ows  = xw;                                        // alias: xw dead after qkv_gemm

    const int prepN = 512 * 1536 + 512 * 512 + 1536;
    prep_kernel<<<dim3((prepN + 255) / 256), dim3(256), 0, stream>>>(
        wq, wk, wv, wo, bq, bk, bv, wqkvT, woT, biasq);
    pre_kernel<<<dim3(8192), dim3(256), 0, stream>>>(x, xw);
    qkv_gemm<<<dim3(3072), dim3(256), 0, stream>>>(xw, wqkvT, biasq, qkvb);
    attn_kernel<<<dim3(1024), dim3(256), 0, stream>>>(qkvb, ows);
    proj_gemm<<<dim3(1024), dim3(256), 0, stream>>>(ows, woT, bo, x, out);
}